// Round 17
// baseline (94.219 us; speedup 1.0000x reference)
//
#include <hip/hip_runtime.h>

#define P_TERMS 24

typedef _Float16 f16x8 __attribute__((ext_vector_type(8)));
typedef float f32x16 __attribute__((ext_vector_type(16)));

static __device__ __forceinline__ unsigned pk2(float a, float b) {
  unsigned d;
  asm("v_cvt_pkrtz_f16_f32 %0, %1, %2" : "=v"(d) : "v"(a), "v"(b));
  return d;
}
// d.lo = a.lo + b.hi ; d.hi = a.hi + b.lo   (f16x2, swapped src1)
static __device__ __forceinline__ unsigned pkadd_sw(unsigned a, unsigned b) {
  unsigned d;
  asm("v_pk_add_f16 %0, %1, %2 op_sel:[0,1] op_sel_hi:[1,0]"
      : "=v"(d) : "v"(a), "v"(b));
  return d;
}

// -------- K0 (fused prep): chain cp[p]=A^pB per block; H8 rows + Ct8 ------
__global__ __launch_bounds__(256) void s4_prep(
    const float* __restrict__ A, const float* __restrict__ B,
    const float* __restrict__ C, const float* __restrict__ log_dt,
    _Float16* __restrict__ H8, _Float16* __restrict__ Ct8) {
  const int tid = threadIdx.x;
  const int bid = blockIdx.x;
  if (bid == 64) {  // Ct8[n/8][m][8] = C[m][n]
    const int m = tid;
#pragma unroll 1
    for (int n = 0; n < 64; ++n)
      Ct8[((size_t)(n >> 3) * 256 + m) * 8 + (n & 7)] = (_Float16)C[m * 64 + n];
    return;
  }
  __shared__ float cp[P_TERMS + 1][64];
  __shared__ float cur[64];
  if (tid < 64) { cur[tid] = B[tid]; cp[0][tid] = B[tid]; }
  __syncthreads();
  const int n = tid >> 2, g = tid & 3;
  for (int p = 1; p <= P_TERMS; ++p) {
    float s = 0.f;
    const int j0 = g * 16;
#pragma unroll
    for (int j = 0; j < 16; ++j) s += A[n * 64 + j0 + j] * cur[j0 + j];
    s += __shfl_xor(s, 1);
    s += __shfl_xor(s, 2);
    __syncthreads();
    if (g == 0) { cur[n] = s; cp[p][n] = s; }
    __syncthreads();
  }
  const float dt = __expf(log_dt[0]);
#pragma unroll 1
  for (int kk = tid; kk < 512; kk += 256) {
    float coef = 1.f, s = cp[0][bid];
#pragma unroll 1
    for (int p = 1; p <= P_TERMS; ++p) {
      coef *= dt * (float)(kk - p + 1) / (float)p;  // zero for p>kk
      s += coef * cp[p][bid];
    }
    H8[((size_t)(kk >> 3) * 64 + bid) * 8 + (kk & 7)] = (_Float16)s;
  }
}

// ---------------- Main: rank-64 factored  Y = dt*(G@H^T)@C^T + 2 u D ------
// 512-thread blocks, 8 waves x 32t strips (half the per-wave tile of R16),
// -> 16 waves/CU for latency hiding. Schedule identical to R16: per wave
// stage1(th0) -> Zl -> INTERLEAVE{stage1(th1) | stage2(th0) panels} ->
// Zl(th1) -> stage2(th1). Zl rows wave-private: no barriers after build.
__global__ __launch_bounds__(512, 4) void s4_main(
    const float* __restrict__ x, const _Float16* __restrict__ H8,
    const _Float16* __restrict__ Ct8, const float* __restrict__ Dvec,
    const float* __restrict__ log_dt, float* __restrict__ out) {
  __shared__ float us[512];
  __shared__ uint4 UF8[1536];
  __shared__ unsigned Zl[256][34];

  const int tid = threadIdx.x;
  const int ch = blockIdx.x;
  const int b = ch >> 8;
  const int d = ch & 255;

  if (tid < 512) us[tid] = x[(b * 512 + tid) * 256 + d];
  __syncthreads();
  {
    const int i0 = tid * 3;  // 512*3 = 1536 windows
    float w[10];
#pragma unroll
    for (int j = 0; j < 10; ++j) {
      const int g = i0 + j - 512;
      const float v = us[g & 511];
      w[j] = (g >= 0 && g < 512) ? v : 0.f;
    }
    unsigned P[9];
#pragma unroll
    for (int j = 0; j < 9; ++j) P[j] = pk2(w[j], w[j + 1]);
#pragma unroll
    for (int e = 0; e < 3; ++e)
      UF8[i0 + e] = make_uint4(P[e], P[e + 2], P[e + 4], P[e + 6]);
  }
  __syncthreads();

  const int lane = tid & 63;
  const int wid = tid >> 6;  // 0..7
  const int r = lane & 31;
  const int hi = lane >> 5;
  const int tw = wid * 32;  // wave strip: 32 t
  const int tl0 = tw + r;   // wave-private Zl row
  const float dtv = __expf(log_dt[0]);

  auto s1_step = [&](int& ifj, int& irj, const _Float16*& hp, f32x16 acc[2]) {
    const uint4 F0 = UF8[ifj];
    const uint4 R0 = UF8[irj];
    const f16x8 h0 = *reinterpret_cast<const f16x8*>(hp);
    const f16x8 h1 = *reinterpret_cast<const f16x8*>(hp + 256);
    union { unsigned w[4]; f16x8 v; } g0;
    g0.w[0] = pkadd_sw(F0.x, R0.w);
    g0.w[1] = pkadd_sw(F0.y, R0.z);
    g0.w[2] = pkadd_sw(F0.z, R0.y);
    g0.w[3] = pkadd_sw(F0.w, R0.x);
    __builtin_amdgcn_s_setprio(1);
    acc[0] = __builtin_amdgcn_mfma_f32_32x32x16_f16(h0, g0.v, acc[0], 0, 0, 0);
    acc[1] = __builtin_amdgcn_mfma_f32_32x32x16_f16(h1, g0.v, acc[1], 0, 0, 0);
    __builtin_amdgcn_s_setprio(0);
    ifj += 16;
    irj -= 16;
    hp += 1024;
  };

  auto writeZ = [&](f32x16 acc[2]) {
#pragma unroll
    for (int ni = 0; ni < 2; ++ni) {
#pragma unroll
      for (int q = 0; q < 4; ++q) {
        uint2 v;
        v.x = pk2(acc[ni][4 * q + 0], acc[ni][4 * q + 1]);
        v.y = pk2(acc[ni][4 * q + 2], acc[ni][4 * q + 3]);
        *reinterpret_cast<uint2*>(&Zl[tl0][ni * 16 + q * 4 + 2 * hi]) = v;
      }
    }
  };

  auto s2_panel = [&](int mp, int th) {
    const int mb2 = mp * 64;
    f32x16 y[2];
#pragma unroll
    for (int mi = 0; mi < 2; ++mi)
#pragma unroll
      for (int e = 0; e < 16; ++e) y[mi][e] = 0.f;
#pragma unroll
    for (int ks = 0; ks < 4; ++ks) {
      const int c0 = 8 * ks + 4 * hi;
      union { uint2 u[2]; f16x8 v; } z0;
      z0.u[0] = *reinterpret_cast<const uint2*>(&Zl[tl0][c0]);
      z0.u[1] = *reinterpret_cast<const uint2*>(&Zl[tl0][c0 + 2]);
      const _Float16* cb = Ct8 + ((size_t)(2 * ks + hi) * 256 + mb2 + r) * 8;
      const f16x8 c0f = *reinterpret_cast<const f16x8*>(cb);
      const f16x8 c1f = *reinterpret_cast<const f16x8*>(cb + 256);
      __builtin_amdgcn_s_setprio(1);
      y[0] = __builtin_amdgcn_mfma_f32_32x32x16_f16(z0.v, c0f, y[0], 0, 0, 0);
      y[1] = __builtin_amdgcn_mfma_f32_32x32x16_f16(z0.v, c1f, y[1], 0, 0, 0);
      __builtin_amdgcn_s_setprio(0);
    }
    const int tb2 = th * 256 + tw + 4 * hi;
#pragma unroll
    for (int mi = 0; mi < 2; ++mi) {
      const int m = mb2 + mi * 32 + r;
      const float Dm = Dvec[m];
#pragma unroll
      for (int reg = 0; reg < 16; ++reg) {
        const int trow = tb2 + (reg & 3) + 8 * (reg >> 2);
        const float uv = us[trow];
        out[(((size_t)b * 512 + trow) * 256 + d) * 256 + m] =
            dtv * y[mi][reg] + 2.f * uv * Dm;
      }
    }
  };

  // ================= schedule =================
  f32x16 acc[2];
#pragma unroll
  for (int ni = 0; ni < 2; ++ni)
#pragma unroll
    for (int e = 0; e < 16; ++e) acc[ni][e] = 0.f;

  {
    int ifj = 512 + tw + r + hi * 8;
    int irj = 505 + tw + r - hi * 8;
    const _Float16* hp = H8 + hi * 512 + r * 8;
#pragma unroll 1
    for (int j = 0; j < 32; ++j) s1_step(ifj, irj, hp, acc);
  }
  writeZ(acc);

  {
    int ifj = 512 + 256 + tw + r + hi * 8;
    int irj = 505 + 256 + tw + r - hi * 8;
    const _Float16* hp = H8 + hi * 512 + r * 8;
    f32x16 acc1[2];
#pragma unroll
    for (int ni = 0; ni < 2; ++ni)
#pragma unroll
      for (int e = 0; e < 16; ++e) acc1[ni][e] = 0.f;

#pragma unroll 1
    for (int s = 0; s < 4; ++s) {
#pragma unroll 1
      for (int j2 = 0; j2 < 8; ++j2) s1_step(ifj, irj, hp, acc1);
      s2_panel(s, 0);
    }
    writeZ(acc1);
  }

#pragma unroll 1
  for (int s = 0; s < 4; ++s) s2_panel(s, 1);
}

extern "C" void kernel_launch(void* const* d_in, const int* in_sizes, int n_in,
                              void* d_out, int out_size, void* d_ws, size_t ws_size,
                              hipStream_t stream) {
  (void)in_sizes; (void)n_in; (void)out_size; (void)ws_size;
  const float* x = (const float*)d_in[0];
  const float* A = (const float*)d_in[1];
  const float* B = (const float*)d_in[2];
  const float* C = (const float*)d_in[3];
  const float* D = (const float*)d_in[4];
  const float* log_dt = (const float*)d_in[5];
  float* out = (float*)d_out;

  _Float16* H8 = (_Float16*)d_ws;                    // 512*64*2 = 64 KB
  _Float16* Ct8 = (_Float16*)((char*)d_ws + 65536);  // 64*256*2 = 32 KB

  s4_prep<<<65, 256, 0, stream>>>(A, B, C, log_dt, H8, Ct8);
  s4_main<<<512, 512, 0, stream>>>(x, H8, Ct8, D, log_dt, out);
}

// Round 18
// 81.638 us; speedup vs baseline: 1.1541x; 1.1541x over previous
//
#include <hip/hip_runtime.h>

#define P_TERMS 24

typedef _Float16 f16x8 __attribute__((ext_vector_type(8)));
typedef float f32x16 __attribute__((ext_vector_type(16)));

static __device__ __forceinline__ unsigned pk2(float a, float b) {
  unsigned d;
  asm("v_cvt_pkrtz_f16_f32 %0, %1, %2" : "=v"(d) : "v"(a), "v"(b));
  return d;
}
// d.lo = a.lo + b.hi ; d.hi = a.hi + b.lo   (f16x2, swapped src1)
static __device__ __forceinline__ unsigned pkadd_sw(unsigned a, unsigned b) {
  unsigned d;
  asm("v_pk_add_f16 %0, %1, %2 op_sel:[0,1] op_sel_hi:[1,0]"
      : "=v"(d) : "v"(a), "v"(b));
  return d;
}

// -------- K0 (fused prep): chain cp[p]=A^pB per block; H8 rows + Ct8 ------
__global__ __launch_bounds__(256) void s4_prep(
    const float* __restrict__ A, const float* __restrict__ B,
    const float* __restrict__ C, const float* __restrict__ log_dt,
    _Float16* __restrict__ H8, _Float16* __restrict__ Ct8) {
  const int tid = threadIdx.x;
  const int bid = blockIdx.x;
  if (bid == 64) {  // Ct8[n/8][m][8] = C[m][n]
    const int m = tid;
#pragma unroll 1
    for (int n = 0; n < 64; ++n)
      Ct8[((size_t)(n >> 3) * 256 + m) * 8 + (n & 7)] = (_Float16)C[m * 64 + n];
    return;
  }
  __shared__ float cp[P_TERMS + 1][64];
  __shared__ float cur[64];
  if (tid < 64) { cur[tid] = B[tid]; cp[0][tid] = B[tid]; }
  __syncthreads();
  const int n = tid >> 2, g = tid & 3;
  for (int p = 1; p <= P_TERMS; ++p) {
    float s = 0.f;
    const int j0 = g * 16;
#pragma unroll
    for (int j = 0; j < 16; ++j) s += A[n * 64 + j0 + j] * cur[j0 + j];
    s += __shfl_xor(s, 1);
    s += __shfl_xor(s, 2);
    __syncthreads();
    if (g == 0) { cur[n] = s; cp[p][n] = s; }
    __syncthreads();
  }
  const float dt = __expf(log_dt[0]);
#pragma unroll 1
  for (int kk = tid; kk < 512; kk += 256) {
    float coef = 1.f, s = cp[0][bid];
#pragma unroll 1
    for (int p = 1; p <= P_TERMS; ++p) {
      coef *= dt * (float)(kk - p + 1) / (float)p;  // zero for p>kk
      s += coef * cp[p][bid];
    }
    H8[((size_t)(kk >> 3) * 64 + bid) * 8 + (kk & 7)] = (_Float16)s;
  }
}

// ---------------- Main: rank-64 factored  Y = dt*(G@H^T)@C^T + 2 u D ------
// One block = one full channel (512 t). Per wave: stage1(th0) -> Zl ->
// INTERLEAVE{ stage1(th1) k-chunks with stage2(th0) store panels } ->
// Zl(th1) -> stage2(th1). Zl rows wave-private: no barriers after build.
__global__ __launch_bounds__(256, 2) void s4_main(
    const float* __restrict__ x, const _Float16* __restrict__ H8,
    const _Float16* __restrict__ Ct8, const float* __restrict__ Dvec,
    const float* __restrict__ log_dt, float* __restrict__ out) {
  __shared__ float us[512];
  __shared__ uint4 UF8[1536];
  __shared__ unsigned Zl[256][34];

  const int tid = threadIdx.x;
  const int ch = blockIdx.x;
  const int b = ch >> 8;
  const int d = ch & 255;

  for (int i = tid; i < 512; i += 256) us[i] = x[(b * 512 + i) * 256 + d];
  __syncthreads();
  {
    const int i0 = tid * 6;
    float w[14];
#pragma unroll
    for (int j = 0; j < 14; ++j) {
      const int g = i0 + j - 512;
      const float v = us[g & 511];
      w[j] = (g >= 0 && g < 512) ? v : 0.f;
    }
    unsigned P[13];
#pragma unroll
    for (int j = 0; j < 13; ++j) P[j] = pk2(w[j], w[j + 1]);
#pragma unroll
    for (int e = 0; e < 6; ++e)
      UF8[i0 + e] = make_uint4(P[e], P[e + 2], P[e + 4], P[e + 6]);
  }
  __syncthreads();

  const int lane = tid & 63;
  const int wid = tid >> 6;
  const int r = lane & 31;
  const int hi = lane >> 5;
  const int tw = wid * 64;
  const int tl0 = tw + r;
  const float dtv = __expf(log_dt[0]);

  auto s1_step = [&](int& ifj, int& irj, const _Float16*& hp, f32x16 acc[2][2]) {
    const uint4 F0 = UF8[ifj];
    const uint4 R0 = UF8[irj];
    const uint4 F1 = UF8[ifj + 32];
    const uint4 R1 = UF8[irj + 32];
    const f16x8 h0 = *reinterpret_cast<const f16x8*>(hp);
    const f16x8 h1 = *reinterpret_cast<const f16x8*>(hp + 256);
    union { unsigned w[4]; f16x8 v; } g0, g1;
    g0.w[0] = pkadd_sw(F0.x, R0.w);
    g0.w[1] = pkadd_sw(F0.y, R0.z);
    g0.w[2] = pkadd_sw(F0.z, R0.y);
    g0.w[3] = pkadd_sw(F0.w, R0.x);
    g1.w[0] = pkadd_sw(F1.x, R1.w);
    g1.w[1] = pkadd_sw(F1.y, R1.z);
    g1.w[2] = pkadd_sw(F1.z, R1.y);
    g1.w[3] = pkadd_sw(F1.w, R1.x);
    __builtin_amdgcn_s_setprio(1);
    acc[0][0] = __builtin_amdgcn_mfma_f32_32x32x16_f16(h0, g0.v, acc[0][0], 0, 0, 0);
    acc[0][1] = __builtin_amdgcn_mfma_f32_32x32x16_f16(h1, g0.v, acc[0][1], 0, 0, 0);
    acc[1][0] = __builtin_amdgcn_mfma_f32_32x32x16_f16(h0, g1.v, acc[1][0], 0, 0, 0);
    acc[1][1] = __builtin_amdgcn_mfma_f32_32x32x16_f16(h1, g1.v, acc[1][1], 0, 0, 0);
    __builtin_amdgcn_s_setprio(0);
    ifj += 16;
    irj -= 16;
    hp += 1024;
  };

  auto writeZ = [&](f32x16 acc[2][2]) {
#pragma unroll
    for (int ti = 0; ti < 2; ++ti) {
      const int t = tl0 + ti * 32;
#pragma unroll
      for (int ni = 0; ni < 2; ++ni) {
#pragma unroll
        for (int q = 0; q < 4; ++q) {
          uint2 v;
          v.x = pk2(acc[ti][ni][4 * q + 0], acc[ti][ni][4 * q + 1]);
          v.y = pk2(acc[ti][ni][4 * q + 2], acc[ti][ni][4 * q + 3]);
          *reinterpret_cast<uint2*>(&Zl[t][ni * 16 + q * 4 + 2 * hi]) = v;
        }
      }
    }
  };

  auto s2_panel = [&](int mp, int th) {
    const int mb2 = mp * 64;
    f32x16 y[2][2];
#pragma unroll
    for (int ti = 0; ti < 2; ++ti)
#pragma unroll
      for (int mi = 0; mi < 2; ++mi)
#pragma unroll
        for (int e = 0; e < 16; ++e) y[ti][mi][e] = 0.f;
#pragma unroll
    for (int ks = 0; ks < 4; ++ks) {
      const int c0 = 8 * ks + 4 * hi;
      union { uint2 u[2]; f16x8 v; } z0, z1;
      z0.u[0] = *reinterpret_cast<const uint2*>(&Zl[tl0][c0]);
      z0.u[1] = *reinterpret_cast<const uint2*>(&Zl[tl0][c0 + 2]);
      z1.u[0] = *reinterpret_cast<const uint2*>(&Zl[tl0 + 32][c0]);
      z1.u[1] = *reinterpret_cast<const uint2*>(&Zl[tl0 + 32][c0 + 2]);
      const _Float16* cb = Ct8 + ((size_t)(2 * ks + hi) * 256 + mb2 + r) * 8;
      const f16x8 c0f = *reinterpret_cast<const f16x8*>(cb);
      const f16x8 c1f = *reinterpret_cast<const f16x8*>(cb + 256);
      __builtin_amdgcn_s_setprio(1);
      y[0][0] = __builtin_amdgcn_mfma_f32_32x32x16_f16(z0.v, c0f, y[0][0], 0, 0, 0);
      y[0][1] = __builtin_amdgcn_mfma_f32_32x32x16_f16(z0.v, c1f, y[0][1], 0, 0, 0);
      y[1][0] = __builtin_amdgcn_mfma_f32_32x32x16_f16(z1.v, c0f, y[1][0], 0, 0, 0);
      y[1][1] = __builtin_amdgcn_mfma_f32_32x32x16_f16(z1.v, c1f, y[1][1], 0, 0, 0);
      __builtin_amdgcn_s_setprio(0);
    }
#pragma unroll
    for (int ti = 0; ti < 2; ++ti) {
      const int tb2 = th * 256 + tw + ti * 32 + 4 * hi;
#pragma unroll
      for (int mi = 0; mi < 2; ++mi) {
        const int m = mb2 + mi * 32 + r;
        const float Dm = Dvec[m];
#pragma unroll
        for (int reg = 0; reg < 16; ++reg) {
          const int trow = tb2 + (reg & 3) + 8 * (reg >> 2);
          const float uv = us[trow];
          out[(((size_t)b * 512 + trow) * 256 + d) * 256 + m] =
              dtv * y[ti][mi][reg] + 2.f * uv * Dm;
        }
      }
    }
  };

  // ================= schedule =================
  f32x16 acc[2][2];
#pragma unroll
  for (int ti = 0; ti < 2; ++ti)
#pragma unroll
    for (int ni = 0; ni < 2; ++ni)
#pragma unroll
      for (int e = 0; e < 16; ++e) acc[ti][ni][e] = 0.f;

  {
    int ifj = 512 + tw + r + hi * 8;
    int irj = 505 + tw + r - hi * 8;
    const _Float16* hp = H8 + hi * 512 + r * 8;
#pragma unroll 1
    for (int j = 0; j < 32; ++j) s1_step(ifj, irj, hp, acc);
  }
  writeZ(acc);

  {
    int ifj = 512 + 256 + tw + r + hi * 8;
    int irj = 505 + 256 + tw + r - hi * 8;
    const _Float16* hp = H8 + hi * 512 + r * 8;
    f32x16 acc1[2][2];
#pragma unroll
    for (int ti = 0; ti < 2; ++ti)
#pragma unroll
      for (int ni = 0; ni < 2; ++ni)
#pragma unroll
        for (int e = 0; e < 16; ++e) acc1[ti][ni][e] = 0.f;

#pragma unroll 1
    for (int s = 0; s < 4; ++s) {
#pragma unroll 1
      for (int j2 = 0; j2 < 8; ++j2) s1_step(ifj, irj, hp, acc1);
      s2_panel(s, 0);
    }
    writeZ(acc1);
  }

#pragma unroll 1
  for (int s = 0; s < 4; ++s) s2_panel(s, 1);
}

extern "C" void kernel_launch(void* const* d_in, const int* in_sizes, int n_in,
                              void* d_out, int out_size, void* d_ws, size_t ws_size,
                              hipStream_t stream) {
  (void)in_sizes; (void)n_in; (void)out_size; (void)ws_size;
  const float* x = (const float*)d_in[0];
  const float* A = (const float*)d_in[1];
  const float* B = (const float*)d_in[2];
  const float* C = (const float*)d_in[3];
  const float* D = (const float*)d_in[4];
  const float* log_dt = (const float*)d_in[5];
  float* out = (float*)d_out;

  _Float16* H8 = (_Float16*)d_ws;                    // 512*64*2 = 64 KB
  _Float16* Ct8 = (_Float16*)((char*)d_ws + 65536);  // 64*256*2 = 32 KB

  s4_prep<<<65, 256, 0, stream>>>(A, B, C, log_dt, H8, Ct8);
  s4_main<<<512, 256, 0, stream>>>(x, H8, Ct8, D, log_dt, out);
}

// Round 19
// 79.199 us; speedup vs baseline: 1.1896x; 1.0308x over previous
//
#include <hip/hip_runtime.h>

#define P_TERMS 24

typedef _Float16 f16x8 __attribute__((ext_vector_type(8)));
typedef float f32x16 __attribute__((ext_vector_type(16)));

static __device__ __forceinline__ unsigned pk2(float a, float b) {
  unsigned d;
  asm("v_cvt_pkrtz_f16_f32 %0, %1, %2" : "=v"(d) : "v"(a), "v"(b));
  return d;
}
// d.lo = a.lo + b.hi ; d.hi = a.hi + b.lo   (f16x2, swapped src1)
static __device__ __forceinline__ unsigned pkadd_sw(unsigned a, unsigned b) {
  unsigned d;
  asm("v_pk_add_f16 %0, %1, %2 op_sel:[0,1] op_sel_hi:[1,0]"
      : "=v"(d) : "v"(a), "v"(b));
  return d;
}

// -------- K0 (fused prep): chain cp[p]=A^pB per block; H8 rows + Ct8 ------
__global__ __launch_bounds__(256) void s4_prep(
    const float* __restrict__ A, const float* __restrict__ B,
    const float* __restrict__ C, const float* __restrict__ log_dt,
    _Float16* __restrict__ H8, _Float16* __restrict__ Ct8) {
  const int tid = threadIdx.x;
  const int bid = blockIdx.x;
  if (bid == 64) {  // Ct8[n/8][m][8] = C[m][n]
    const int m = tid;
#pragma unroll 1
    for (int n = 0; n < 64; ++n)
      Ct8[((size_t)(n >> 3) * 256 + m) * 8 + (n & 7)] = (_Float16)C[m * 64 + n];
    return;
  }
  __shared__ float cp[P_TERMS + 1][64];
  __shared__ float cur[64];
  if (tid < 64) { cur[tid] = B[tid]; cp[0][tid] = B[tid]; }
  __syncthreads();
  const int n = tid >> 2, g = tid & 3;
  for (int p = 1; p <= P_TERMS; ++p) {
    float s = 0.f;
    const int j0 = g * 16;
#pragma unroll
    for (int j = 0; j < 16; ++j) s += A[n * 64 + j0 + j] * cur[j0 + j];
    s += __shfl_xor(s, 1);
    s += __shfl_xor(s, 2);
    __syncthreads();
    if (g == 0) { cur[n] = s; cp[p][n] = s; }
    __syncthreads();
  }
  const float dt = __expf(log_dt[0]);
#pragma unroll 1
  for (int kk = tid; kk < 512; kk += 256) {
    float coef = 1.f, s = cp[0][bid];
#pragma unroll 1
    for (int p = 1; p <= P_TERMS; ++p) {
      coef *= dt * (float)(kk - p + 1) / (float)p;  // zero for p>kk
      s += coef * cp[p][bid];
    }
    H8[((size_t)(kk >> 3) * 64 + bid) * 8 + (kk & 7)] = (_Float16)s;
  }
}

// ---------------- Main: rank-64 factored  Y = dt*(G@H^T)@C^T + 2 u D ------
// R18 schedule, but s2_panel epilogue repacks y through wave-private LDS
// scratch into float4 (16B/lane) stores: 16 dwordx4 per panel instead of
// 64 scalar dword stores (fill-kernel payload shape).
__global__ __launch_bounds__(256, 2) void s4_main(
    const float* __restrict__ x, const _Float16* __restrict__ H8,
    const _Float16* __restrict__ Ct8, const float* __restrict__ Dvec,
    const float* __restrict__ log_dt, float* __restrict__ out) {
  __shared__ float us[512];
  __shared__ uint4 UF8[1536];
  __shared__ unsigned Zl[256][34];
  __shared__ float S[4][8][68];  // per-wave repack scratch (rows 272B: 16B-aligned)

  const int tid = threadIdx.x;
  const int ch = blockIdx.x;
  const int b = ch >> 8;
  const int d = ch & 255;

  for (int i = tid; i < 512; i += 256) us[i] = x[(b * 512 + i) * 256 + d];
  __syncthreads();
  {
    const int i0 = tid * 6;
    float w[14];
#pragma unroll
    for (int j = 0; j < 14; ++j) {
      const int g = i0 + j - 512;
      const float v = us[g & 511];
      w[j] = (g >= 0 && g < 512) ? v : 0.f;
    }
    unsigned P[13];
#pragma unroll
    for (int j = 0; j < 13; ++j) P[j] = pk2(w[j], w[j + 1]);
#pragma unroll
    for (int e = 0; e < 6; ++e)
      UF8[i0 + e] = make_uint4(P[e], P[e + 2], P[e + 4], P[e + 6]);
  }
  __syncthreads();

  const int lane = tid & 63;
  const int wid = tid >> 6;
  const int r = lane & 31;
  const int hi = lane >> 5;
  const int tw = wid * 64;
  const int tl0 = tw + r;
  const float dtv = __expf(log_dt[0]);

  auto s1_step = [&](int& ifj, int& irj, const _Float16*& hp, f32x16 acc[2][2]) {
    const uint4 F0 = UF8[ifj];
    const uint4 R0 = UF8[irj];
    const uint4 F1 = UF8[ifj + 32];
    const uint4 R1 = UF8[irj + 32];
    const f16x8 h0 = *reinterpret_cast<const f16x8*>(hp);
    const f16x8 h1 = *reinterpret_cast<const f16x8*>(hp + 256);
    union { unsigned w[4]; f16x8 v; } g0, g1;
    g0.w[0] = pkadd_sw(F0.x, R0.w);
    g0.w[1] = pkadd_sw(F0.y, R0.z);
    g0.w[2] = pkadd_sw(F0.z, R0.y);
    g0.w[3] = pkadd_sw(F0.w, R0.x);
    g1.w[0] = pkadd_sw(F1.x, R1.w);
    g1.w[1] = pkadd_sw(F1.y, R1.z);
    g1.w[2] = pkadd_sw(F1.z, R1.y);
    g1.w[3] = pkadd_sw(F1.w, R1.x);
    __builtin_amdgcn_s_setprio(1);
    acc[0][0] = __builtin_amdgcn_mfma_f32_32x32x16_f16(h0, g0.v, acc[0][0], 0, 0, 0);
    acc[0][1] = __builtin_amdgcn_mfma_f32_32x32x16_f16(h1, g0.v, acc[0][1], 0, 0, 0);
    acc[1][0] = __builtin_amdgcn_mfma_f32_32x32x16_f16(h0, g1.v, acc[1][0], 0, 0, 0);
    acc[1][1] = __builtin_amdgcn_mfma_f32_32x32x16_f16(h1, g1.v, acc[1][1], 0, 0, 0);
    __builtin_amdgcn_s_setprio(0);
    ifj += 16;
    irj -= 16;
    hp += 1024;
  };

  auto writeZ = [&](f32x16 acc[2][2]) {
#pragma unroll
    for (int ti = 0; ti < 2; ++ti) {
      const int t = tl0 + ti * 32;
#pragma unroll
      for (int ni = 0; ni < 2; ++ni) {
#pragma unroll
        for (int q = 0; q < 4; ++q) {
          uint2 v;
          v.x = pk2(acc[ti][ni][4 * q + 0], acc[ti][ni][4 * q + 1]);
          v.y = pk2(acc[ti][ni][4 * q + 2], acc[ti][ni][4 * q + 3]);
          *reinterpret_cast<uint2*>(&Zl[t][ni * 16 + q * 4 + 2 * hi]) = v;
        }
      }
    }
  };

  auto s2_panel = [&](int mp, int th) {
    const int mb2 = mp * 64;
    f32x16 y[2][2];
#pragma unroll
    for (int ti = 0; ti < 2; ++ti)
#pragma unroll
      for (int mi = 0; mi < 2; ++mi)
#pragma unroll
        for (int e = 0; e < 16; ++e) y[ti][mi][e] = 0.f;
#pragma unroll
    for (int ks = 0; ks < 4; ++ks) {
      const int c0 = 8 * ks + 4 * hi;
      union { uint2 u[2]; f16x8 v; } z0, z1;
      z0.u[0] = *reinterpret_cast<const uint2*>(&Zl[tl0][c0]);
      z0.u[1] = *reinterpret_cast<const uint2*>(&Zl[tl0][c0 + 2]);
      z1.u[0] = *reinterpret_cast<const uint2*>(&Zl[tl0 + 32][c0]);
      z1.u[1] = *reinterpret_cast<const uint2*>(&Zl[tl0 + 32][c0 + 2]);
      const _Float16* cb = Ct8 + ((size_t)(2 * ks + hi) * 256 + mb2 + r) * 8;
      const f16x8 c0f = *reinterpret_cast<const f16x8*>(cb);
      const f16x8 c1f = *reinterpret_cast<const f16x8*>(cb + 256);
      __builtin_amdgcn_s_setprio(1);
      y[0][0] = __builtin_amdgcn_mfma_f32_32x32x16_f16(z0.v, c0f, y[0][0], 0, 0, 0);
      y[0][1] = __builtin_amdgcn_mfma_f32_32x32x16_f16(z0.v, c1f, y[0][1], 0, 0, 0);
      y[1][0] = __builtin_amdgcn_mfma_f32_32x32x16_f16(z1.v, c0f, y[1][0], 0, 0, 0);
      y[1][1] = __builtin_amdgcn_mfma_f32_32x32x16_f16(z1.v, c1f, y[1][1], 0, 0, 0);
      __builtin_amdgcn_s_setprio(0);
    }

    // epilogue: wave-private LDS repack -> float4 stores (16B/lane)
    const float Dm0 = Dvec[mb2 + r];
    const float Dm1 = Dvec[mb2 + 32 + r];
#pragma unroll
    for (int ti = 0; ti < 2; ++ti) {
      const int tbq0 = th * 256 + tw + ti * 32;
#pragma unroll
      for (int q = 0; q < 4; ++q) {
        const int tbase = tbq0 + 8 * q;
#pragma unroll
        for (int j = 0; j < 4; ++j) {
          const int rr = 4 * hi + j;  // S row <-> trow = tbase + rr
          const float uv2 = 2.f * us[tbase + rr];
          S[wid][rr][r] = dtv * y[ti][0][4 * q + j] + uv2 * Dm0;
          S[wid][rr][32 + r] = dtv * y[ti][1][4 * q + j] + uv2 * Dm1;
        }
#pragma unroll
        for (int k = 0; k < 2; ++k) {
          const int flat = k * 64 + lane;
          const int row = flat >> 4;  // 4 rows per instr, 16 float4/row
          const int c4 = flat & 15;
          const float4 v = *reinterpret_cast<const float4*>(&S[wid][row][c4 * 4]);
          *reinterpret_cast<float4*>(
              &out[(((size_t)b * 512 + tbase + row) * 256 + d) * 256 + mb2 +
                   c4 * 4]) = v;
        }
      }
    }
  };

  // ================= schedule =================
  f32x16 acc[2][2];
#pragma unroll
  for (int ti = 0; ti < 2; ++ti)
#pragma unroll
    for (int ni = 0; ni < 2; ++ni)
#pragma unroll
      for (int e = 0; e < 16; ++e) acc[ti][ni][e] = 0.f;

  {
    int ifj = 512 + tw + r + hi * 8;
    int irj = 505 + tw + r - hi * 8;
    const _Float16* hp = H8 + hi * 512 + r * 8;
#pragma unroll 1
    for (int j = 0; j < 32; ++j) s1_step(ifj, irj, hp, acc);
  }
  writeZ(acc);

  {
    int ifj = 512 + 256 + tw + r + hi * 8;
    int irj = 505 + 256 + tw + r - hi * 8;
    const _Float16* hp = H8 + hi * 512 + r * 8;
    f32x16 acc1[2][2];
#pragma unroll
    for (int ti = 0; ti < 2; ++ti)
#pragma unroll
      for (int ni = 0; ni < 2; ++ni)
#pragma unroll
        for (int e = 0; e < 16; ++e) acc1[ti][ni][e] = 0.f;

#pragma unroll 1
    for (int s = 0; s < 4; ++s) {
#pragma unroll 1
      for (int j2 = 0; j2 < 8; ++j2) s1_step(ifj, irj, hp, acc1);
      s2_panel(s, 0);
    }
    writeZ(acc1);
  }

#pragma unroll 1
  for (int s = 0; s < 4; ++s) s2_panel(s, 1);
}

extern "C" void kernel_launch(void* const* d_in, const int* in_sizes, int n_in,
                              void* d_out, int out_size, void* d_ws, size_t ws_size,
                              hipStream_t stream) {
  (void)in_sizes; (void)n_in; (void)out_size; (void)ws_size;
  const float* x = (const float*)d_in[0];
  const float* A = (const float*)d_in[1];
  const float* B = (const float*)d_in[2];
  const float* C = (const float*)d_in[3];
  const float* D = (const float*)d_in[4];
  const float* log_dt = (const float*)d_in[5];
  float* out = (float*)d_out;

  _Float16* H8 = (_Float16*)d_ws;                    // 512*64*2 = 64 KB
  _Float16* Ct8 = (_Float16*)((char*)d_ws + 65536);  // 64*256*2 = 32 KB

  s4_prep<<<65, 256, 0, stream>>>(A, B, C, log_dt, H8, Ct8);
  s4_main<<<512, 256, 0, stream>>>(x, H8, Ct8, D, log_dt, out);
}

// Round 20
// 78.832 us; speedup vs baseline: 1.1952x; 1.0047x over previous
//
#include <hip/hip_runtime.h>

#define P_TERMS 24

typedef _Float16 f16x8 __attribute__((ext_vector_type(8)));
typedef float f32x16 __attribute__((ext_vector_type(16)));

static __device__ __forceinline__ unsigned pk2(float a, float b) {
  unsigned d;
  asm("v_cvt_pkrtz_f16_f32 %0, %1, %2" : "=v"(d) : "v"(a), "v"(b));
  return d;
}
// d.lo = a.lo + b.hi ; d.hi = a.hi + b.lo   (f16x2, swapped src1)
static __device__ __forceinline__ unsigned pkadd_sw(unsigned a, unsigned b) {
  unsigned d;
  asm("v_pk_add_f16 %0, %1, %2 op_sel:[0,1] op_sel_hi:[1,0]"
      : "=v"(d) : "v"(a), "v"(b));
  return d;
}

// -------- K0 (fused prep): A^pB chain -> H8; Ct8; x -> xT transpose -------
__global__ __launch_bounds__(256) void s4_prep(
    const float* __restrict__ A, const float* __restrict__ B,
    const float* __restrict__ C, const float* __restrict__ log_dt,
    const float* __restrict__ x, _Float16* __restrict__ H8,
    _Float16* __restrict__ Ct8, float* __restrict__ xT) {
  const int tid = threadIdx.x;
  const int bid = blockIdx.x;
  if (bid == 64) {  // Ct8[n/8][m][8] = C[m][n]
    const int m = tid;
#pragma unroll 1
    for (int n = 0; n < 64; ++n)
      Ct8[((size_t)(n >> 3) * 256 + m) * 8 + (n & 7)] = (_Float16)C[m * 64 + n];
    return;
  }
  if (bid > 64) {  // transpose x[b][t][d] -> xT[b][d][t], 32x32 tiles
    __shared__ float tile[32][33];
    const int ti = bid - 65;        // 0..255
    const int b = ti >> 7;          // 2 batches x 128 tiles
    const int tt = (ti >> 3) & 15;  // t-tile
    const int dd = ti & 7;          // d-tile
    const int t0 = tt * 32, d0 = dd * 32;
    const int tx = tid & 31, ty = tid >> 5;  // 32 x 8
#pragma unroll
    for (int i = 0; i < 4; ++i) {
      const int row = ty + i * 8;
      tile[row][tx] = x[((size_t)b * 512 + t0 + row) * 256 + d0 + tx];
    }
    __syncthreads();
#pragma unroll
    for (int i = 0; i < 4; ++i) {
      const int row = ty + i * 8;
      xT[((size_t)b * 256 + d0 + row) * 512 + t0 + tx] = tile[tx][row];
    }
    return;
  }
  __shared__ float cp[P_TERMS + 1][64];
  __shared__ float cur[64];
  if (tid < 64) { cur[tid] = B[tid]; cp[0][tid] = B[tid]; }
  __syncthreads();
  const int n = tid >> 2, g = tid & 3;
  for (int p = 1; p <= P_TERMS; ++p) {
    float s = 0.f;
    const int j0 = g * 16;
#pragma unroll
    for (int j = 0; j < 16; ++j) s += A[n * 64 + j0 + j] * cur[j0 + j];
    s += __shfl_xor(s, 1);
    s += __shfl_xor(s, 2);
    __syncthreads();
    if (g == 0) { cur[n] = s; cp[p][n] = s; }
    __syncthreads();
  }
  const float dt = __expf(log_dt[0]);
#pragma unroll 1
  for (int kk = tid; kk < 512; kk += 256) {
    float coef = 1.f, s = cp[0][bid];
#pragma unroll 1
    for (int p = 1; p <= P_TERMS; ++p) {
      coef *= dt * (float)(kk - p + 1) / (float)p;  // zero for p>kk
      s += coef * cp[p][bid];
    }
    H8[((size_t)(kk >> 3) * 64 + bid) * 8 + (kk & 7)] = (_Float16)s;
  }
}

// ---------------- Main: rank-64 factored  Y = dt*(G@H^T)@C^T + 2 u D ------
// R19 structure (interleaved schedule, wave-private Zl, wide-store
// epilogue via LDS repack); prolog now reads coalesced xT rows.
__global__ __launch_bounds__(256, 2) void s4_main(
    const float* __restrict__ xT, const _Float16* __restrict__ H8,
    const _Float16* __restrict__ Ct8, const float* __restrict__ Dvec,
    const float* __restrict__ log_dt, float* __restrict__ out) {
  __shared__ float us[512];
  __shared__ uint4 UF8[1536];
  __shared__ unsigned Zl[256][34];
  __shared__ float S[4][8][68];  // per-wave repack scratch

  const int tid = threadIdx.x;
  const int ch = blockIdx.x;
  const int b = ch >> 8;
  const int d = ch & 255;

  for (int i = tid; i < 512; i += 256)
    us[i] = xT[((size_t)b * 256 + d) * 512 + i];
  __syncthreads();
  {
    const int i0 = tid * 6;
    float w[14];
#pragma unroll
    for (int j = 0; j < 14; ++j) {
      const int g = i0 + j - 512;
      const float v = us[g & 511];
      w[j] = (g >= 0 && g < 512) ? v : 0.f;
    }
    unsigned P[13];
#pragma unroll
    for (int j = 0; j < 13; ++j) P[j] = pk2(w[j], w[j + 1]);
#pragma unroll
    for (int e = 0; e < 6; ++e)
      UF8[i0 + e] = make_uint4(P[e], P[e + 2], P[e + 4], P[e + 6]);
  }
  __syncthreads();

  const int lane = tid & 63;
  const int wid = tid >> 6;
  const int r = lane & 31;
  const int hi = lane >> 5;
  const int tw = wid * 64;
  const int tl0 = tw + r;
  const float dtv = __expf(log_dt[0]);

  auto s1_step = [&](int& ifj, int& irj, const _Float16*& hp, f32x16 acc[2][2]) {
    const uint4 F0 = UF8[ifj];
    const uint4 R0 = UF8[irj];
    const uint4 F1 = UF8[ifj + 32];
    const uint4 R1 = UF8[irj + 32];
    const f16x8 h0 = *reinterpret_cast<const f16x8*>(hp);
    const f16x8 h1 = *reinterpret_cast<const f16x8*>(hp + 256);
    union { unsigned w[4]; f16x8 v; } g0, g1;
    g0.w[0] = pkadd_sw(F0.x, R0.w);
    g0.w[1] = pkadd_sw(F0.y, R0.z);
    g0.w[2] = pkadd_sw(F0.z, R0.y);
    g0.w[3] = pkadd_sw(F0.w, R0.x);
    g1.w[0] = pkadd_sw(F1.x, R1.w);
    g1.w[1] = pkadd_sw(F1.y, R1.z);
    g1.w[2] = pkadd_sw(F1.z, R1.y);
    g1.w[3] = pkadd_sw(F1.w, R1.x);
    __builtin_amdgcn_s_setprio(1);
    acc[0][0] = __builtin_amdgcn_mfma_f32_32x32x16_f16(h0, g0.v, acc[0][0], 0, 0, 0);
    acc[0][1] = __builtin_amdgcn_mfma_f32_32x32x16_f16(h1, g0.v, acc[0][1], 0, 0, 0);
    acc[1][0] = __builtin_amdgcn_mfma_f32_32x32x16_f16(h0, g1.v, acc[1][0], 0, 0, 0);
    acc[1][1] = __builtin_amdgcn_mfma_f32_32x32x16_f16(h1, g1.v, acc[1][1], 0, 0, 0);
    __builtin_amdgcn_s_setprio(0);
    ifj += 16;
    irj -= 16;
    hp += 1024;
  };

  auto writeZ = [&](f32x16 acc[2][2]) {
#pragma unroll
    for (int ti = 0; ti < 2; ++ti) {
      const int t = tl0 + ti * 32;
#pragma unroll
      for (int ni = 0; ni < 2; ++ni) {
#pragma unroll
        for (int q = 0; q < 4; ++q) {
          uint2 v;
          v.x = pk2(acc[ti][ni][4 * q + 0], acc[ti][ni][4 * q + 1]);
          v.y = pk2(acc[ti][ni][4 * q + 2], acc[ti][ni][4 * q + 3]);
          *reinterpret_cast<uint2*>(&Zl[t][ni * 16 + q * 4 + 2 * hi]) = v;
        }
      }
    }
  };

  auto s2_panel = [&](int mp, int th) {
    const int mb2 = mp * 64;
    f32x16 y[2][2];
#pragma unroll
    for (int ti = 0; ti < 2; ++ti)
#pragma unroll
      for (int mi = 0; mi < 2; ++mi)
#pragma unroll
        for (int e = 0; e < 16; ++e) y[ti][mi][e] = 0.f;
#pragma unroll
    for (int ks = 0; ks < 4; ++ks) {
      const int c0 = 8 * ks + 4 * hi;
      union { uint2 u[2]; f16x8 v; } z0, z1;
      z0.u[0] = *reinterpret_cast<const uint2*>(&Zl[tl0][c0]);
      z0.u[1] = *reinterpret_cast<const uint2*>(&Zl[tl0][c0 + 2]);
      z1.u[0] = *reinterpret_cast<const uint2*>(&Zl[tl0 + 32][c0]);
      z1.u[1] = *reinterpret_cast<const uint2*>(&Zl[tl0 + 32][c0 + 2]);
      const _Float16* cb = Ct8 + ((size_t)(2 * ks + hi) * 256 + mb2 + r) * 8;
      const f16x8 c0f = *reinterpret_cast<const f16x8*>(cb);
      const f16x8 c1f = *reinterpret_cast<const f16x8*>(cb + 256);
      __builtin_amdgcn_s_setprio(1);
      y[0][0] = __builtin_amdgcn_mfma_f32_32x32x16_f16(z0.v, c0f, y[0][0], 0, 0, 0);
      y[0][1] = __builtin_amdgcn_mfma_f32_32x32x16_f16(z0.v, c1f, y[0][1], 0, 0, 0);
      y[1][0] = __builtin_amdgcn_mfma_f32_32x32x16_f16(z1.v, c0f, y[1][0], 0, 0, 0);
      y[1][1] = __builtin_amdgcn_mfma_f32_32x32x16_f16(z1.v, c1f, y[1][1], 0, 0, 0);
      __builtin_amdgcn_s_setprio(0);
    }

    // epilogue: wave-private LDS repack -> float4 stores (16B/lane)
    const float Dm0 = Dvec[mb2 + r];
    const float Dm1 = Dvec[mb2 + 32 + r];
#pragma unroll
    for (int ti = 0; ti < 2; ++ti) {
      const int tbq0 = th * 256 + tw + ti * 32;
#pragma unroll
      for (int q = 0; q < 4; ++q) {
        const int tbase = tbq0 + 8 * q;
#pragma unroll
        for (int j = 0; j < 4; ++j) {
          const int rr = 4 * hi + j;  // S row <-> trow = tbase + rr
          const float uv2 = 2.f * us[tbase + rr];
          S[wid][rr][r] = dtv * y[ti][0][4 * q + j] + uv2 * Dm0;
          S[wid][rr][32 + r] = dtv * y[ti][1][4 * q + j] + uv2 * Dm1;
        }
#pragma unroll
        for (int k = 0; k < 2; ++k) {
          const int flat = k * 64 + lane;
          const int row = flat >> 4;
          const int c4 = flat & 15;
          const float4 v = *reinterpret_cast<const float4*>(&S[wid][row][c4 * 4]);
          *reinterpret_cast<float4*>(
              &out[(((size_t)b * 512 + tbase + row) * 256 + d) * 256 + mb2 +
                   c4 * 4]) = v;
        }
      }
    }
  };

  // ================= schedule =================
  f32x16 acc[2][2];
#pragma unroll
  for (int ti = 0; ti < 2; ++ti)
#pragma unroll
    for (int ni = 0; ni < 2; ++ni)
#pragma unroll
      for (int e = 0; e < 16; ++e) acc[ti][ni][e] = 0.f;

  {
    int ifj = 512 + tw + r + hi * 8;
    int irj = 505 + tw + r - hi * 8;
    const _Float16* hp = H8 + hi * 512 + r * 8;
#pragma unroll 1
    for (int j = 0; j < 32; ++j) s1_step(ifj, irj, hp, acc);
  }
  writeZ(acc);

  {
    int ifj = 512 + 256 + tw + r + hi * 8;
    int irj = 505 + 256 + tw + r - hi * 8;
    const _Float16* hp = H8 + hi * 512 + r * 8;
    f32x16 acc1[2][2];
#pragma unroll
    for (int ti = 0; ti < 2; ++ti)
#pragma unroll
      for (int ni = 0; ni < 2; ++ni)
#pragma unroll
        for (int e = 0; e < 16; ++e) acc1[ti][ni][e] = 0.f;

#pragma unroll 1
    for (int s = 0; s < 4; ++s) {
#pragma unroll 1
      for (int j2 = 0; j2 < 8; ++j2) s1_step(ifj, irj, hp, acc1);
      s2_panel(s, 0);
    }
    writeZ(acc1);
  }

#pragma unroll 1
  for (int s = 0; s < 4; ++s) s2_panel(s, 1);
}

extern "C" void kernel_launch(void* const* d_in, const int* in_sizes, int n_in,
                              void* d_out, int out_size, void* d_ws, size_t ws_size,
                              hipStream_t stream) {
  (void)in_sizes; (void)n_in; (void)out_size; (void)ws_size;
  const float* x = (const float*)d_in[0];
  const float* A = (const float*)d_in[1];
  const float* B = (const float*)d_in[2];
  const float* C = (const float*)d_in[3];
  const float* D = (const float*)d_in[4];
  const float* log_dt = (const float*)d_in[5];
  float* out = (float*)d_out;

  _Float16* H8 = (_Float16*)d_ws;                    // 512*64*2 = 64 KB
  _Float16* Ct8 = (_Float16*)((char*)d_ws + 65536);  // 64*256*2 = 32 KB
  float* xT = (float*)((char*)d_ws + 98304);         // 2*256*512*4 = 1 MB

  s4_prep<<<321, 256, 0, stream>>>(A, B, C, log_dt, x, H8, Ct8, xT);
  s4_main<<<512, 256, 0, stream>>>(xT, H8, Ct8, D, log_dt, out);
}

// Round 21
// 71.204 us; speedup vs baseline: 1.3232x; 1.1071x over previous
//
#include <hip/hip_runtime.h>

#define P_TERMS 24

typedef _Float16 f16x8 __attribute__((ext_vector_type(8)));
typedef float f32x16 __attribute__((ext_vector_type(16)));

static __device__ __forceinline__ unsigned pk2(float a, float b) {
  unsigned d;
  asm("v_cvt_pkrtz_f16_f32 %0, %1, %2" : "=v"(d) : "v"(a), "v"(b));
  return d;
}
// d.lo = a.lo + b.hi ; d.hi = a.hi + b.lo   (f16x2, swapped src1)
static __device__ __forceinline__ unsigned pkadd_sw(unsigned a, unsigned b) {
  unsigned d;
  asm("v_pk_add_f16 %0, %1, %2 op_sel:[0,1] op_sel_hi:[1,0]"
      : "=v"(d) : "v"(a), "v"(b));
  return d;
}

// -------- K0 (fused prep): A^pB chain -> H8; Ct8; x -> xT transpose -------
__global__ __launch_bounds__(256) void s4_prep(
    const float* __restrict__ A, const float* __restrict__ B,
    const float* __restrict__ C, const float* __restrict__ log_dt,
    const float* __restrict__ x, _Float16* __restrict__ H8,
    _Float16* __restrict__ Ct8, float* __restrict__ xT) {
  const int tid = threadIdx.x;
  const int bid = blockIdx.x;
  if (bid == 64) {  // Ct8[n/8][m][8] = C[m][n]
    const int m = tid;
#pragma unroll 1
    for (int n = 0; n < 64; ++n)
      Ct8[((size_t)(n >> 3) * 256 + m) * 8 + (n & 7)] = (_Float16)C[m * 64 + n];
    return;
  }
  if (bid > 64) {  // transpose x[b][t][d] -> xT[b][d][t], 32x32 tiles
    __shared__ float tile[32][33];
    const int ti = bid - 65;        // 0..255
    const int b = ti >> 7;          // 2 batches x 128 tiles
    const int tt = (ti >> 3) & 15;  // t-tile
    const int dd = ti & 7;          // d-tile
    const int t0 = tt * 32, d0 = dd * 32;
    const int tx = tid & 31, ty = tid >> 5;  // 32 x 8
#pragma unroll
    for (int i = 0; i < 4; ++i) {
      const int row = ty + i * 8;
      tile[row][tx] = x[((size_t)b * 512 + t0 + row) * 256 + d0 + tx];
    }
    __syncthreads();
#pragma unroll
    for (int i = 0; i < 4; ++i) {
      const int row = ty + i * 8;
      xT[((size_t)b * 256 + d0 + row) * 512 + t0 + tx] = tile[tx][row];
    }
    return;
  }
  __shared__ float cp[P_TERMS + 1][64];
  __shared__ float cur[64];
  if (tid < 64) { cur[tid] = B[tid]; cp[0][tid] = B[tid]; }
  __syncthreads();
  const int n = tid >> 2, g = tid & 3;
  for (int p = 1; p <= P_TERMS; ++p) {
    float s = 0.f;
    const int j0 = g * 16;
#pragma unroll
    for (int j = 0; j < 16; ++j) s += A[n * 64 + j0 + j] * cur[j0 + j];
    s += __shfl_xor(s, 1);
    s += __shfl_xor(s, 2);
    __syncthreads();
    if (g == 0) { cur[n] = s; cp[p][n] = s; }
    __syncthreads();
  }
  const float dt = __expf(log_dt[0]);
#pragma unroll 1
  for (int kk = tid; kk < 512; kk += 256) {
    float coef = 1.f, s = cp[0][bid];
#pragma unroll 1
    for (int p = 1; p <= P_TERMS; ++p) {
      coef *= dt * (float)(kk - p + 1) / (float)p;  // zero for p>kk
      s += coef * cp[p][bid];
    }
    H8[((size_t)(kk >> 3) * 64 + bid) * 8 + (kk & 7)] = (_Float16)s;
  }
}

// ---------------- Main: rank-64 factored  Y = dt*(G@H^T)@C^T + 2 u D ------
// R20 structure + zero-block skipping in stage-1: kstep j contributes 0
// iff j >= jmax = max(32 - T, T + 4), T = tg0/16 (both F and R quads are
// all-zero for every lane). Skips 48/256 wave-ksteps (18.75%) bit-exactly.
__global__ __launch_bounds__(256, 2) void s4_main(
    const float* __restrict__ xT, const _Float16* __restrict__ H8,
    const _Float16* __restrict__ Ct8, const float* __restrict__ Dvec,
    const float* __restrict__ log_dt, float* __restrict__ out) {
  __shared__ float us[512];
  __shared__ uint4 UF8[1536];
  __shared__ unsigned Zl[256][34];
  __shared__ float S[4][8][68];  // per-wave repack scratch

  const int tid = threadIdx.x;
  const int ch = blockIdx.x;
  const int b = ch >> 8;
  const int d = ch & 255;

  for (int i = tid; i < 512; i += 256)
    us[i] = xT[((size_t)b * 256 + d) * 512 + i];
  __syncthreads();
  {
    const int i0 = tid * 6;
    float w[14];
#pragma unroll
    for (int j = 0; j < 14; ++j) {
      const int g = i0 + j - 512;
      const float v = us[g & 511];
      w[j] = (g >= 0 && g < 512) ? v : 0.f;
    }
    unsigned P[13];
#pragma unroll
    for (int j = 0; j < 13; ++j) P[j] = pk2(w[j], w[j + 1]);
#pragma unroll
    for (int e = 0; e < 6; ++e)
      UF8[i0 + e] = make_uint4(P[e], P[e + 2], P[e + 4], P[e + 6]);
  }
  __syncthreads();

  const int lane = tid & 63;
  const int wid = tid >> 6;
  const int r = lane & 31;
  const int hi = lane >> 5;
  const int tw = wid * 64;
  const int tl0 = tw + r;
  const float dtv = __expf(log_dt[0]);

  auto s1_step = [&](int& ifj, int& irj, const _Float16*& hp, f32x16 acc[2][2]) {
    const uint4 F0 = UF8[ifj];
    const uint4 R0 = UF8[irj];
    const uint4 F1 = UF8[ifj + 32];
    const uint4 R1 = UF8[irj + 32];
    const f16x8 h0 = *reinterpret_cast<const f16x8*>(hp);
    const f16x8 h1 = *reinterpret_cast<const f16x8*>(hp + 256);
    union { unsigned w[4]; f16x8 v; } g0, g1;
    g0.w[0] = pkadd_sw(F0.x, R0.w);
    g0.w[1] = pkadd_sw(F0.y, R0.z);
    g0.w[2] = pkadd_sw(F0.z, R0.y);
    g0.w[3] = pkadd_sw(F0.w, R0.x);
    g1.w[0] = pkadd_sw(F1.x, R1.w);
    g1.w[1] = pkadd_sw(F1.y, R1.z);
    g1.w[2] = pkadd_sw(F1.z, R1.y);
    g1.w[3] = pkadd_sw(F1.w, R1.x);
    __builtin_amdgcn_s_setprio(1);
    acc[0][0] = __builtin_amdgcn_mfma_f32_32x32x16_f16(h0, g0.v, acc[0][0], 0, 0, 0);
    acc[0][1] = __builtin_amdgcn_mfma_f32_32x32x16_f16(h1, g0.v, acc[0][1], 0, 0, 0);
    acc[1][0] = __builtin_amdgcn_mfma_f32_32x32x16_f16(h0, g1.v, acc[1][0], 0, 0, 0);
    acc[1][1] = __builtin_amdgcn_mfma_f32_32x32x16_f16(h1, g1.v, acc[1][1], 0, 0, 0);
    __builtin_amdgcn_s_setprio(0);
    ifj += 16;
    irj -= 16;
    hp += 1024;
  };

  auto writeZ = [&](f32x16 acc[2][2]) {
#pragma unroll
    for (int ti = 0; ti < 2; ++ti) {
      const int t = tl0 + ti * 32;
#pragma unroll
      for (int ni = 0; ni < 2; ++ni) {
#pragma unroll
        for (int q = 0; q < 4; ++q) {
          uint2 v;
          v.x = pk2(acc[ti][ni][4 * q + 0], acc[ti][ni][4 * q + 1]);
          v.y = pk2(acc[ti][ni][4 * q + 2], acc[ti][ni][4 * q + 3]);
          *reinterpret_cast<uint2*>(&Zl[t][ni * 16 + q * 4 + 2 * hi]) = v;
        }
      }
    }
  };

  auto s2_panel = [&](int mp, int th) {
    const int mb2 = mp * 64;
    f32x16 y[2][2];
#pragma unroll
    for (int ti = 0; ti < 2; ++ti)
#pragma unroll
      for (int mi = 0; mi < 2; ++mi)
#pragma unroll
        for (int e = 0; e < 16; ++e) y[ti][mi][e] = 0.f;
#pragma unroll
    for (int ks = 0; ks < 4; ++ks) {
      const int c0 = 8 * ks + 4 * hi;
      union { uint2 u[2]; f16x8 v; } z0, z1;
      z0.u[0] = *reinterpret_cast<const uint2*>(&Zl[tl0][c0]);
      z0.u[1] = *reinterpret_cast<const uint2*>(&Zl[tl0][c0 + 2]);
      z1.u[0] = *reinterpret_cast<const uint2*>(&Zl[tl0 + 32][c0]);
      z1.u[1] = *reinterpret_cast<const uint2*>(&Zl[tl0 + 32][c0 + 2]);
      const _Float16* cb = Ct8 + ((size_t)(2 * ks + hi) * 256 + mb2 + r) * 8;
      const f16x8 c0f = *reinterpret_cast<const f16x8*>(cb);
      const f16x8 c1f = *reinterpret_cast<const f16x8*>(cb + 256);
      __builtin_amdgcn_s_setprio(1);
      y[0][0] = __builtin_amdgcn_mfma_f32_32x32x16_f16(z0.v, c0f, y[0][0], 0, 0, 0);
      y[0][1] = __builtin_amdgcn_mfma_f32_32x32x16_f16(z0.v, c1f, y[0][1], 0, 0, 0);
      y[1][0] = __builtin_amdgcn_mfma_f32_32x32x16_f16(z1.v, c0f, y[1][0], 0, 0, 0);
      y[1][1] = __builtin_amdgcn_mfma_f32_32x32x16_f16(z1.v, c1f, y[1][1], 0, 0, 0);
      __builtin_amdgcn_s_setprio(0);
    }

    // epilogue: wave-private LDS repack -> float4 stores (16B/lane)
    const float Dm0 = Dvec[mb2 + r];
    const float Dm1 = Dvec[mb2 + 32 + r];
#pragma unroll
    for (int ti = 0; ti < 2; ++ti) {
      const int tbq0 = th * 256 + tw + ti * 32;
#pragma unroll
      for (int q = 0; q < 4; ++q) {
        const int tbase = tbq0 + 8 * q;
#pragma unroll
        for (int j = 0; j < 4; ++j) {
          const int rr = 4 * hi + j;  // S row <-> trow = tbase + rr
          const float uv2 = 2.f * us[tbase + rr];
          S[wid][rr][r] = dtv * y[ti][0][4 * q + j] + uv2 * Dm0;
          S[wid][rr][32 + r] = dtv * y[ti][1][4 * q + j] + uv2 * Dm1;
        }
#pragma unroll
        for (int k = 0; k < 2; ++k) {
          const int flat = k * 64 + lane;
          const int row = flat >> 4;
          const int c4 = flat & 15;
          const float4 v = *reinterpret_cast<const float4*>(&S[wid][row][c4 * 4]);
          *reinterpret_cast<float4*>(
              &out[(((size_t)b * 512 + tbase + row) * 256 + d) * 256 + mb2 +
                   c4 * 4]) = v;
        }
      }
    }
  };

  // ================= schedule =================
  f32x16 acc[2][2];
#pragma unroll
  for (int ti = 0; ti < 2; ++ti)
#pragma unroll
    for (int ni = 0; ni < 2; ++ni)
#pragma unroll
      for (int e = 0; e < 16; ++e) acc[ti][ni][e] = 0.f;

  {
    // th=0: tg0 = tw; skip ksteps where both F and R quads are all-zero
    const int T0 = tw >> 4;
    const int jmax0 = (32 - T0 > T0 + 4) ? (32 - T0) : (T0 + 4);
    int ifj = 512 + tw + r + hi * 8;
    int irj = 505 + tw + r - hi * 8;
    const _Float16* hp = H8 + hi * 512 + r * 8;
#pragma unroll 1
    for (int j = 0; j < jmax0; ++j) s1_step(ifj, irj, hp, acc);
  }
  writeZ(acc);

  {
    // th=1: tg0 = 256 + tw
    const int T1 = (256 + tw) >> 4;
    const int jmax1 = (32 - T1 > T1 + 4) ? (32 - T1) : (T1 + 4);
    int ifj = 512 + 256 + tw + r + hi * 8;
    int irj = 505 + 256 + tw + r - hi * 8;
    const _Float16* hp = H8 + hi * 512 + r * 8;
    f32x16 acc1[2][2];
#pragma unroll
    for (int ti = 0; ti < 2; ++ti)
#pragma unroll
      for (int ni = 0; ni < 2; ++ni)
#pragma unroll
        for (int e = 0; e < 16; ++e) acc1[ti][ni][e] = 0.f;

#pragma unroll 1
    for (int s = 0; s < 4; ++s) {
#pragma unroll 1
      for (int j2 = 0; j2 < 8; ++j2) {
        if (8 * s + j2 < jmax1) s1_step(ifj, irj, hp, acc1);
      }
      s2_panel(s, 0);
    }
    writeZ(acc1);
  }

#pragma unroll 1
  for (int s = 0; s < 4; ++s) s2_panel(s, 1);
}

extern "C" void kernel_launch(void* const* d_in, const int* in_sizes, int n_in,
                              void* d_out, int out_size, void* d_ws, size_t ws_size,
                              hipStream_t stream) {
  (void)in_sizes; (void)n_in; (void)out_size; (void)ws_size;
  const float* x = (const float*)d_in[0];
  const float* A = (const float*)d_in[1];
  const float* B = (const float*)d_in[2];
  const float* C = (const float*)d_in[3];
  const float* D = (const float*)d_in[4];
  const float* log_dt = (const float*)d_in[5];
  float* out = (float*)d_out;

  _Float16* H8 = (_Float16*)d_ws;                    // 512*64*2 = 64 KB
  _Float16* Ct8 = (_Float16*)((char*)d_ws + 65536);  // 64*256*2 = 32 KB
  float* xT = (float*)((char*)d_ws + 98304);         // 2*256*512*4 = 1 MB

  s4_prep<<<321, 256, 0, stream>>>(A, B, C, log_dt, x, H8, Ct8, xT);
  s4_main<<<512, 256, 0, stream>>>(xT, H8, Ct8, D, log_dt, out);
}